// Round 3
// baseline (5441.779 us; speedup 1.0000x reference)
//
#include <hip/hip_runtime.h>
#include <stdint.h>

#define B_ 32
#define T_ 512
#define E_ 256
#define U_ 512
#define N3U_ 1536

typedef __bf16 bf16_t;
typedef bf16_t bf16x8 __attribute__((ext_vector_type(8)));
typedef float f32x4 __attribute__((ext_vector_type(4)));

__device__ __forceinline__ unsigned short f2bf(float x) {
    union { float f; unsigned int u; } v; v.f = x;
    return (unsigned short)((v.u + 0x7fffu + ((v.u >> 16) & 1u)) >> 16);
}
__device__ __forceinline__ float bf2f(unsigned short h) {
    union { unsigned int u; float f; } v; v.u = ((unsigned int)h) << 16;
    return v.f;
}

// ---------- Kernel 1: xp[dir] = bf16( bf16(emb[tokens]) @ bf16(W) + b_in ) ----------
// grid (24, 256, 2), block 256. 64x64 tile, K=256 in two 128-halves. bf16 out to ws.
// (unchanged — proven)
__global__ __launch_bounds__(256) void gemm_xproj(
    const int* __restrict__ tokens, const float* __restrict__ emb,
    const float* __restrict__ Wf, const float* __restrict__ Wb,
    const float* __restrict__ binf, const float* __restrict__ binb,
    unsigned short* __restrict__ xpf, unsigned short* __restrict__ xpb)
{
    const int dir = blockIdx.z;
    const float* W   = dir ? Wb   : Wf;
    const float* bin = dir ? binb : binf;
    unsigned short* xp = dir ? xpb : xpf;

    const int n0 = blockIdx.x << 6;
    const int m0 = blockIdx.y << 6;
    const int tid  = threadIdx.x;
    const int lane = tid & 63;
    const int w    = tid >> 6;

    __shared__ __align__(16) unsigned short Ash[64][136];
    __shared__ __align__(16) unsigned short Bsh[64][136];

    f32x4 acc[4];
    for (int f = 0; f < 4; ++f) acc[f] = (f32x4){0.f, 0.f, 0.f, 0.f};

    for (int kt = 0; kt < 2; ++kt) {
        const int kbase = kt << 7;
        for (int p = 0; p < 8; ++p) {
            int row = (p << 3) + (tid >> 5);
            int c   = tid & 31;
            int tok = tokens[m0 + row];
            float4 v = *(const float4*)&emb[tok * E_ + kbase + (c << 2)];
            ushort4 o;
            o.x = f2bf(v.x); o.y = f2bf(v.y); o.z = f2bf(v.z); o.w = f2bf(v.w);
            *(ushort4*)&Ash[row][c << 2] = o;
        }
        for (int p = 0; p < 8; ++p) {
            int kl = (p << 4) + (tid >> 4);
            int j4 = (tid & 15) << 2;
            float4 v = *(const float4*)&W[(kbase + kl) * N3U_ + n0 + j4];
            Bsh[j4 + 0][kl] = f2bf(v.x);
            Bsh[j4 + 1][kl] = f2bf(v.y);
            Bsh[j4 + 2][kl] = f2bf(v.z);
            Bsh[j4 + 3][kl] = f2bf(v.w);
        }
        __syncthreads();
        for (int ks = 0; ks < 4; ++ks) {
            int off = (ks << 5) + ((lane >> 4) << 3);
            bf16x8 a = *(const bf16x8*)&Ash[(w << 4) + (lane & 15)][off];
            for (int f = 0; f < 4; ++f) {
                bf16x8 b = *(const bf16x8*)&Bsh[(f << 4) + (lane & 15)][off];
                acc[f] = __builtin_amdgcn_mfma_f32_16x16x32_bf16(a, b, acc[f], 0, 0, 0);
            }
        }
        __syncthreads();
    }
    const int col_l = lane & 15;
    const int mrow  = (w << 4) + ((lane >> 4) << 2);
    for (int f = 0; f < 4; ++f) {
        int col = n0 + (f << 4) + col_l;
        float bb = bin[col];
        for (int r = 0; r < 4; ++r) {
            int m = m0 + mrow + r;
            xp[m * N3U_ + col] = f2bf(acc[f][r] + bb);
        }
    }
}

// ---------- Kernel 2: bidirectional masked GRU scan, weight-stationary MFMA ----------
// R8 change (group-degree reduction): 32 blocks = dir(2) x mg(2) x us(8); each block
// owns a 64-u x 3-gate slice (wfrag[4][3][4], 192 VGPR/wave, launch_bounds(256,1)).
// Rationale (R2 post-mortem): per-step cost is dominated by all 32 group members
// re-reading the group's whole h (64KB) at AGENT scope (IF$/MALL congestion) plus a
// skew-max over 32 producers — not by the barrier (its removal was neutral). 8-block
// groups cut the bypass-read traffic and poll requests 4x and the skew tail to
// max-of-8, while per-block MFMA time (~0.25us) stays far below the 4.2us step time.
// Same tagged-u64 {tag=step+1, hi/lo bf16} protocol as R2 (lap-safety: every block's
// read set includes every producer's slice, so no producer can run ahead).
__global__ __launch_bounds__(256, 1) void gru_scan(
    const unsigned short* __restrict__ xpf, const unsigned short* __restrict__ xpb,
    const float* __restrict__ Uf, const float* __restrict__ Ub,
    const float* __restrict__ brf, const float* __restrict__ brb,
    const int* __restrict__ tokens,
    unsigned long long* __restrict__ hpk,
    float* __restrict__ out)
{
    const int bx  = blockIdx.x;
    const int us  = bx & 7;            // 8 u-slices of 64
    const int mg  = (bx >> 3) & 1;
    const int dir = bx >> 4;
    const int u0  = us << 6;
    const int tid  = threadIdx.x;
    const int lane = tid & 63;
    const int w    = tid >> 6;

    const unsigned short* xp = dir ? xpb : xpf;
    const float* Uw = dir ? Ub : Uf;
    const float* br = dir ? brb : brf;

    __shared__ __align__(16) unsigned short Ahi[16][520];
    __shared__ __align__(16) unsigned short Alo[16][520];
    __shared__ __align__(16) float red[12 * 1088];  // [g*4+w][16 rows][stride 68]

    // stationary weight fragments: wave w covers k in [w*128, w*128+128),
    // cols = 3 gates x 4 col-frags of 16 within [u0, u0+64)
    bf16x8 wfrag[4][3][4];
    const int quad = lane >> 4, nl = lane & 15;
    for (int ks = 0; ks < 4; ++ks)
        for (int g = 0; g < 3; ++g)
            for (int cf = 0; cf < 4; ++cf) {
                union { bf16x8 v; unsigned short s[8]; } uu;
                for (int j = 0; j < 8; ++j) {
                    int k   = (w << 7) + (ks << 5) + (quad << 3) + j;
                    int col = (g << 9) + u0 + (cf << 4) + nl;
                    uu.s[j] = f2bf(Uw[k * N3U_ + col]);
                }
                wfrag[ks][g][cf] = uu.v;
            }

    const int bl  = tid >> 4;                 // local batch row 0..15
    const int ug0 = u0 + ((tid & 15) << 2);   // 4 u-columns per thread
    const int bg  = (mg << 4) + bl;           // global batch
    const int cc  = tid << 1;                 // poll column pair (u64 units)
    float hreg[4] = {0.f, 0.f, 0.f, 0.f};
    const float4 brzv = *(const float4*)&br[ug0];
    const float4 brrv = *(const float4*)&br[512 + ug0];
    const float4 brhv = *(const float4*)&br[1024 + ug0];

    for (int s = 0; s < T_; ++s) {
        const int t    = dir ? (T_ - 1 - s) : s;
        const int bufr = s & 1, bufw = bufr ^ 1;

        // early independent loads (consumed in epilogue)
        const int xrow = (bg * T_ + t) * N3U_;
        const ushort4 xzv = *(const ushort4*)&xp[xrow + ug0];
        const ushort4 xrv = *(const ushort4*)&xp[xrow + 512 + ug0];
        const ushort4 xhv = *(const ushort4*)&xp[xrow + 1024 + ug0];
        const int tok = tokens[bg * T_ + t];

        // ---- poll-load this mg's 16 rows of tagged h (2 u64 per thread per row) ----
        const int hbase = (((bufr << 1) + dir) << 14) + (mg << 13) + cc;
        const unsigned int exp_tag = (unsigned int)s;
        unsigned long long hva[16], hvb[16];
#pragma unroll
        for (int q = 0; q < 16; ++q) {
            hva[q] = __hip_atomic_load(&hpk[hbase + (q << 9)],
                                       __ATOMIC_RELAXED, __HIP_MEMORY_SCOPE_AGENT);
            hvb[q] = __hip_atomic_load(&hpk[hbase + (q << 9) + 1],
                                       __ATOMIC_RELAXED, __HIP_MEMORY_SCOPE_AGENT);
        }
        unsigned int badA = 0u, badB = 0u;
#pragma unroll
        for (int q = 0; q < 16; ++q) {
            badA |= ((unsigned int)(hva[q] >> 32) != exp_tag) ? (1u << q) : 0u;
            badB |= ((unsigned int)(hvb[q] >> 32) != exp_tag) ? (1u << q) : 0u;
        }
        while (badA | badB) {
            __builtin_amdgcn_s_sleep(1);
#pragma unroll
            for (int q = 0; q < 16; ++q) {
                if (badA & (1u << q))
                    hva[q] = __hip_atomic_load(&hpk[hbase + (q << 9)],
                                               __ATOMIC_RELAXED, __HIP_MEMORY_SCOPE_AGENT);
                if (badB & (1u << q))
                    hvb[q] = __hip_atomic_load(&hpk[hbase + (q << 9) + 1],
                                               __ATOMIC_RELAXED, __HIP_MEMORY_SCOPE_AGENT);
            }
#pragma unroll
            for (int q = 0; q < 16; ++q) {
                if ((unsigned int)(hva[q] >> 32) == exp_tag) badA &= ~(1u << q);
                if ((unsigned int)(hvb[q] >> 32) == exp_tag) badB &= ~(1u << q);
            }
        }
        // unpack to LDS (hi plane + lo plane)
#pragma unroll
        for (int q = 0; q < 16; ++q) {
            unsigned int dA = (unsigned int)hva[q];
            unsigned int dB = (unsigned int)hvb[q];
            *(unsigned int*)&Ahi[q][cc] = (dA & 0xffffu) | (dB << 16);
            *(unsigned int*)&Alo[q][cc] = (dA >> 16) | (dB & 0xffff0000u);
        }
        __syncthreads();

        f32x4 acc[3][4];
#pragma unroll
        for (int g = 0; g < 3; ++g)
#pragma unroll
            for (int cf = 0; cf < 4; ++cf)
                acc[g][cf] = (f32x4){0.f, 0.f, 0.f, 0.f};
        for (int ks = 0; ks < 4; ++ks) {
            int off = (w << 7) + (ks << 5) + (quad << 3);
            bf16x8 ahi = *(const bf16x8*)&Ahi[nl][off];
            bf16x8 alo = *(const bf16x8*)&Alo[nl][off];
#pragma unroll
            for (int g = 0; g < 3; ++g)
#pragma unroll
                for (int cf = 0; cf < 4; ++cf) {
                    acc[g][cf] = __builtin_amdgcn_mfma_f32_16x16x32_bf16(ahi, wfrag[ks][g][cf], acc[g][cf], 0, 0, 0);
                    acc[g][cf] = __builtin_amdgcn_mfma_f32_16x16x32_bf16(alo, wfrag[ks][g][cf], acc[g][cf], 0, 0, 0);
                }
        }
        // cross-wave (k-split) partials to LDS: row=quad*4+r (0..15), col=cf*16+nl (0..63)
#pragma unroll
        for (int g = 0; g < 3; ++g)
#pragma unroll
            for (int cf = 0; cf < 4; ++cf)
#pragma unroll
                for (int r = 0; r < 4; ++r)
                    red[(((g << 2) + w) * 1088) + ((quad << 2) + r) * 68 + (cf << 4) + nl] = acc[g][cf][r];
        __syncthreads();

        // per-thread epilogue over its 4 u-columns
        const int rb = bl * 68 + ((tid & 15) << 2);
        const int hwb = (((bufw << 1) + dir) << 14) + (bg << 9) + ug0;
        float4 ov;
#pragma unroll
        for (int j = 0; j < 4; ++j) {
            float rz = brzv[j], rr = brrv[j], rh = brhv[j];
#pragma unroll
            for (int ww = 0; ww < 4; ++ww) {
                rz += red[(0 + ww) * 1088 + rb + j];
                rr += red[(4 + ww) * 1088 + rb + j];
                rh += red[(8 + ww) * 1088 + rb + j];
            }
            float xz = bf2f(((const unsigned short*)&xzv)[j]);
            float xr = bf2f(((const unsigned short*)&xrv)[j]);
            float xh = bf2f(((const unsigned short*)&xhv)[j]);
            float z    = 1.f / (1.f + expf(-(xz + rz)));
            float rg   = 1.f / (1.f + expf(-(xr + rr)));
            float cand = tanhf(xh + rg * rh);
            float hn   = z * hreg[j] + (1.f - z) * cand;
            float ho   = (tok != 0) ? hn : hreg[j];   // Keras masking: carry state
            hreg[j] = ho;
            ov[j] = ho;

            // publish h FIRST (critical path): one 8B atomic = {tag, data}
            unsigned short hi = f2bf(ho);
            unsigned short lo = f2bf(ho - bf2f(hi));
            unsigned long long pv =
                ((unsigned long long)(unsigned int)(s + 1) << 32)
                | (unsigned long long)(((unsigned int)lo << 16) | (unsigned int)hi);
            __hip_atomic_store(&hpk[hwb + j], pv, __ATOMIC_RELAXED, __HIP_MEMORY_SCOPE_AGENT);
        }

        *(float4*)&out[(bg * T_ + t) * 1024 + (dir << 9) + ug0] = ov;  // off critical path
    }
}

extern "C" void kernel_launch(void* const* d_in, const int* in_sizes, int n_in,
                              void* d_out, int out_size, void* d_ws, size_t ws_size,
                              hipStream_t stream)
{
    const size_t XP_BYTES  = (size_t)B_ * T_ * N3U_ * 2;    // 50,331,648 per dir (bf16)
    const size_t H_OFF     = 2 * XP_BYTES;                  // 100,663,296
    const size_t HPK_BYTES = (size_t)2 * 2 * 32 * 512 * 8;  // 524,288 (2 bufs x 2 dirs, u64 tagged)
    const size_t NEED      = H_OFF + HPK_BYTES;
    if (ws_size < NEED) return;  // fail visibly

    const int*   tokens = (const int*)d_in[0];
    const float* emb    = (const float*)d_in[1];
    const float* W_fw   = (const float*)d_in[2];
    const float* U_fw   = (const float*)d_in[3];
    const float* bin_fw = (const float*)d_in[4];
    const float* brc_fw = (const float*)d_in[5];
    const float* W_bw   = (const float*)d_in[6];
    const float* U_bw   = (const float*)d_in[7];
    const float* bin_bw = (const float*)d_in[8];
    const float* brc_bw = (const float*)d_in[9];

    char* ws = (char*)d_ws;
    unsigned short* xpf = (unsigned short*)ws;
    unsigned short* xpb = (unsigned short*)(ws + XP_BYTES);
    unsigned long long* hpk = (unsigned long long*)(ws + H_OFF);
    float* outp = (float*)d_out;

    // zero tagged h state (both buffers => tag 0 == step-0 expected, data 0), every call
    hipMemsetAsync(ws + H_OFF, 0, HPK_BYTES, stream);

    gemm_xproj<<<dim3(24, 256, 2), dim3(256), 0, stream>>>(
        tokens, emb, W_fw, W_bw, bin_fw, bin_bw, xpf, xpb);

    void* args[] = { (void*)&xpf, (void*)&xpb, (void*)&U_fw, (void*)&U_bw,
                     (void*)&brc_fw, (void*)&brc_bw, (void*)&tokens,
                     (void*)&hpk, (void*)&outp };
    hipLaunchCooperativeKernel((const void*)gru_scan, dim3(32), dim3(256), args, 0, stream);
}

// Round 4
// 2301.832 us; speedup vs baseline: 2.3641x; 2.3641x over previous
//
#include <hip/hip_runtime.h>
#include <stdint.h>

#define B_ 32
#define T_ 512
#define E_ 256
#define U_ 512
#define N3U_ 1536

typedef __bf16 bf16_t;
typedef bf16_t bf16x8 __attribute__((ext_vector_type(8)));
typedef float f32x4 __attribute__((ext_vector_type(4)));

__device__ __forceinline__ unsigned short f2bf(float x) {
    union { float f; unsigned int u; } v; v.f = x;
    return (unsigned short)((v.u + 0x7fffu + ((v.u >> 16) & 1u)) >> 16);
}
__device__ __forceinline__ float bf2f(unsigned short h) {
    union { unsigned int u; float f; } v; v.u = ((unsigned int)h) << 16;
    return v.f;
}
// fast sigmoid/tanh on the serial critical path (v_exp_f32-based, branchless,
// overflow-safe; |err| ~1e-6 << 2^-10 tolerance)
__device__ __forceinline__ float fsigmoid(float x) {
    return 1.f / (1.f + __expf(-x));
}
__device__ __forceinline__ float ftanh(float x) {
    float ax = fabsf(x);
    float e  = __expf(-2.f * ax);          // <= 1, no overflow
    float t  = (1.f - e) / (1.f + e);
    return copysignf(t, x);
}

// ---------- Kernel 1: xp[dir] = bf16( bf16(emb[tokens]) @ bf16(W) + b_in ) ----------
// (unchanged — proven)
__global__ __launch_bounds__(256) void gemm_xproj(
    const int* __restrict__ tokens, const float* __restrict__ emb,
    const float* __restrict__ Wf, const float* __restrict__ Wb,
    const float* __restrict__ binf, const float* __restrict__ binb,
    unsigned short* __restrict__ xpf, unsigned short* __restrict__ xpb)
{
    const int dir = blockIdx.z;
    const float* W   = dir ? Wb   : Wf;
    const float* bin = dir ? binb : binf;
    unsigned short* xp = dir ? xpb : xpf;

    const int n0 = blockIdx.x << 6;
    const int m0 = blockIdx.y << 6;
    const int tid  = threadIdx.x;
    const int lane = tid & 63;
    const int w    = tid >> 6;

    __shared__ __align__(16) unsigned short Ash[64][136];
    __shared__ __align__(16) unsigned short Bsh[64][136];

    f32x4 acc[4];
    for (int f = 0; f < 4; ++f) acc[f] = (f32x4){0.f, 0.f, 0.f, 0.f};

    for (int kt = 0; kt < 2; ++kt) {
        const int kbase = kt << 7;
        for (int p = 0; p < 8; ++p) {
            int row = (p << 3) + (tid >> 5);
            int c   = tid & 31;
            int tok = tokens[m0 + row];
            float4 v = *(const float4*)&emb[tok * E_ + kbase + (c << 2)];
            ushort4 o;
            o.x = f2bf(v.x); o.y = f2bf(v.y); o.z = f2bf(v.z); o.w = f2bf(v.w);
            *(ushort4*)&Ash[row][c << 2] = o;
        }
        for (int p = 0; p < 8; ++p) {
            int kl = (p << 4) + (tid >> 4);
            int j4 = (tid & 15) << 2;
            float4 v = *(const float4*)&W[(kbase + kl) * N3U_ + n0 + j4];
            Bsh[j4 + 0][kl] = f2bf(v.x);
            Bsh[j4 + 1][kl] = f2bf(v.y);
            Bsh[j4 + 2][kl] = f2bf(v.z);
            Bsh[j4 + 3][kl] = f2bf(v.w);
        }
        __syncthreads();
        for (int ks = 0; ks < 4; ++ks) {
            int off = (ks << 5) + ((lane >> 4) << 3);
            bf16x8 a = *(const bf16x8*)&Ash[(w << 4) + (lane & 15)][off];
            for (int f = 0; f < 4; ++f) {
                bf16x8 b = *(const bf16x8*)&Bsh[(f << 4) + (lane & 15)][off];
                acc[f] = __builtin_amdgcn_mfma_f32_16x16x32_bf16(a, b, acc[f], 0, 0, 0);
            }
        }
        __syncthreads();
    }
    const int col_l = lane & 15;
    const int mrow  = (w << 4) + ((lane >> 4) << 2);
    for (int f = 0; f < 4; ++f) {
        int col = n0 + (f << 4) + col_l;
        float bb = bin[col];
        for (int r = 0; r < 4; ++r) {
            int m = m0 + mrow + r;
            xp[m * N3U_ + col] = f2bf(acc[f][r] + bb);
        }
    }
}

// ---------- Kernel 2: bidirectional masked GRU scan, weight-stationary MFMA ----------
// R9: 64 blocks = dir(2) x mg(2) x us(16), 512 threads (8 waves: wk(4) k-quarter x
// wc(2) 16-col half). Single-variable test of the R2 congestion theory: halves the
// number of polling consumers (MALL read traffic 8MB -> 4MB/step) and the skew
// degree (32 -> 16 producers), while keeping all per-wave state register-resident
// (wfrag 48 + poll 32 + acc 12 VGPR — the R3 spill is structurally impossible here).
// Same proven tagged-u64 {tag=step+1, lo16|hi16} protocol (lap-safety: every
// consumer reads every producer's slice every step).
#define RED(wc, g, wk, row, col) (((((wc)*3 + (g))*4 + (wk))*16 + (row))*18 + (col))
__global__ __launch_bounds__(512, 2) void gru_scan(
    const unsigned short* __restrict__ xpf, const unsigned short* __restrict__ xpb,
    const float* __restrict__ Uf, const float* __restrict__ Ub,
    const float* __restrict__ brf, const float* __restrict__ brb,
    const int* __restrict__ tokens,
    unsigned long long* __restrict__ hpk,
    float* __restrict__ out)
{
    const int bx  = blockIdx.x;
    const int us  = bx & 15;           // 16 u-slices of 32
    const int mg  = (bx >> 4) & 1;
    const int dir = bx >> 5;
    const int u0  = us << 5;
    const int tid  = threadIdx.x;
    const int lane = tid & 63;
    const int w    = tid >> 6;         // 0..7
    const int wk   = w & 3;            // k-quarter
    const int wc   = w >> 2;           // 16-col half

    const unsigned short* xp = dir ? xpb : xpf;
    const float* Uw = dir ? Ub : Uf;
    const float* br = dir ? brb : brf;

    __shared__ __align__(16) unsigned short Ahi[16][520];
    __shared__ __align__(16) unsigned short Alo[16][520];
    __shared__ __align__(16) float red[2 * 3 * 4 * 16 * 18];   // 27.6 KB

    // stationary weights: wave (wk,wc): k in [wk*128,(wk+1)*128), cols = 3 gates x
    // 16 cols at u0 + wc*16
    bf16x8 wfrag[4][3];
    const int quad = lane >> 4, nl = lane & 15;
    for (int ks = 0; ks < 4; ++ks)
        for (int g = 0; g < 3; ++g) {
            union { bf16x8 v; unsigned short s[8]; } uu;
            for (int j = 0; j < 8; ++j) {
                int k   = (wk << 7) + (ks << 5) + (quad << 3) + j;
                int col = (g << 9) + u0 + (wc << 4) + nl;
                uu.s[j] = f2bf(Uw[k * N3U_ + col]);
            }
            wfrag[ks][g] = uu.v;
        }

    // epilogue ownership: 1 output per thread
    const int bl = tid >> 5;           // local batch row 0..15
    const int cl = tid & 31;           // local u 0..31
    const int ewc = cl >> 4, ec16 = cl & 15;
    const int bg = (mg << 4) + bl;     // global batch row
    const int ug = u0 + cl;            // global u
    float hreg = 0.f;
    const float brz = br[ug], brr = br[512 + ug], brh = br[1024 + ug];

    for (int s = 0; s < T_; ++s) {
        const int t    = dir ? (T_ - 1 - s) : s;
        const int bufr = s & 1, bufw = bufr ^ 1;

        // early independent loads (consumed in epilogue)
        const int xrow = (bg * T_ + t) * N3U_;
        const unsigned short xzu = xp[xrow + ug];
        const unsigned short xru = xp[xrow + 512 + ug];
        const unsigned short xhu = xp[xrow + 1024 + ug];
        const int tok = tokens[bg * T_ + t];

        // ---- poll-load this mg's 16 rows of tagged h: 1 u64 per thread per row ----
        const int hbase = (((bufr << 1) + dir) << 14) + (mg << 13) + tid;
        const unsigned int exp_tag = (unsigned int)s;
        unsigned long long hv[16];
#pragma unroll
        for (int q = 0; q < 16; ++q)
            hv[q] = __hip_atomic_load(&hpk[hbase + (q << 9)],
                                      __ATOMIC_RELAXED, __HIP_MEMORY_SCOPE_AGENT);
        unsigned int bad = 0u;
#pragma unroll
        for (int q = 0; q < 16; ++q)
            bad |= ((unsigned int)(hv[q] >> 32) != exp_tag) ? (1u << q) : 0u;
        while (bad) {
            __builtin_amdgcn_s_sleep(1);
#pragma unroll
            for (int q = 0; q < 16; ++q)
                if (bad & (1u << q))
                    hv[q] = __hip_atomic_load(&hpk[hbase + (q << 9)],
                                              __ATOMIC_RELAXED, __HIP_MEMORY_SCOPE_AGENT);
#pragma unroll
            for (int q = 0; q < 16; ++q)
                if ((unsigned int)(hv[q] >> 32) == exp_tag) bad &= ~(1u << q);
        }
        // unpack to LDS planes: Ahi/Alo[row][u], u = tid
#pragma unroll
        for (int q = 0; q < 16; ++q) {
            unsigned int d = (unsigned int)hv[q];
            Ahi[q][tid] = (unsigned short)(d & 0xffffu);
            Alo[q][tid] = (unsigned short)(d >> 16);
        }
        __syncthreads();

        f32x4 acc[3];
        acc[0] = (f32x4){0.f,0.f,0.f,0.f};
        acc[1] = (f32x4){0.f,0.f,0.f,0.f};
        acc[2] = (f32x4){0.f,0.f,0.f,0.f};
        for (int ks = 0; ks < 4; ++ks) {
            int off = (wk << 7) + (ks << 5) + (quad << 3);
            bf16x8 ahi = *(const bf16x8*)&Ahi[nl][off];
            bf16x8 alo = *(const bf16x8*)&Alo[nl][off];
#pragma unroll
            for (int g = 0; g < 3; ++g) {
                acc[g] = __builtin_amdgcn_mfma_f32_16x16x32_bf16(ahi, wfrag[ks][g], acc[g], 0, 0, 0);
                acc[g] = __builtin_amdgcn_mfma_f32_16x16x32_bf16(alo, wfrag[ks][g], acc[g], 0, 0, 0);
            }
        }
        // k-split partials to LDS: row=(quad*4+r), col=nl for this (wc,wk)
#pragma unroll
        for (int g = 0; g < 3; ++g)
#pragma unroll
            for (int r = 0; r < 4; ++r)
                red[RED(wc, g, wk, (quad << 2) + r, nl)] = acc[g][r];
        __syncthreads();

        // per-thread epilogue (1 output)
        float rz = brz, rr = brr, rh = brh;
#pragma unroll
        for (int k4 = 0; k4 < 4; ++k4) {
            rz += red[RED(ewc, 0, k4, bl, ec16)];
            rr += red[RED(ewc, 1, k4, bl, ec16)];
            rh += red[RED(ewc, 2, k4, bl, ec16)];
        }
        float xz = bf2f(xzu), xr = bf2f(xru), xh = bf2f(xhu);
        float z    = fsigmoid(xz + rz);
        float rg   = fsigmoid(xr + rr);
        float cand = ftanh(xh + rg * rh);
        float hn   = z * hreg + (1.f - z) * cand;
        float ho   = (tok != 0) ? hn : hreg;   // Keras masking: carry state
        hreg = ho;

        // publish h FIRST (critical path): one 8B atomic = {tag, data}
        unsigned short hi = f2bf(ho);
        unsigned short lo = f2bf(ho - bf2f(hi));
        int hw = (((bufw << 1) + dir) << 14) + (bg << 9) + ug;
        unsigned long long pv =
            ((unsigned long long)(unsigned int)(s + 1) << 32)
            | (unsigned long long)(((unsigned int)lo << 16) | (unsigned int)hi);
        __hip_atomic_store(&hpk[hw], pv, __ATOMIC_RELAXED, __HIP_MEMORY_SCOPE_AGENT);

        out[(bg * T_ + t) * 1024 + (dir << 9) + ug] = ho;   // off critical path
    }
}

extern "C" void kernel_launch(void* const* d_in, const int* in_sizes, int n_in,
                              void* d_out, int out_size, void* d_ws, size_t ws_size,
                              hipStream_t stream)
{
    const size_t XP_BYTES  = (size_t)B_ * T_ * N3U_ * 2;    // 50,331,648 per dir (bf16)
    const size_t H_OFF     = 2 * XP_BYTES;                  // 100,663,296
    const size_t HPK_BYTES = (size_t)2 * 2 * 32 * 512 * 8;  // 524,288 (2 bufs x 2 dirs, u64 tagged)
    const size_t NEED      = H_OFF + HPK_BYTES;
    if (ws_size < NEED) return;  // fail visibly

    const int*   tokens = (const int*)d_in[0];
    const float* emb    = (const float*)d_in[1];
    const float* W_fw   = (const float*)d_in[2];
    const float* U_fw   = (const float*)d_in[3];
    const float* bin_fw = (const float*)d_in[4];
    const float* brc_fw = (const float*)d_in[5];
    const float* W_bw   = (const float*)d_in[6];
    const float* U_bw   = (const float*)d_in[7];
    const float* bin_bw = (const float*)d_in[8];
    const float* brc_bw = (const float*)d_in[9];

    char* ws = (char*)d_ws;
    unsigned short* xpf = (unsigned short*)ws;
    unsigned short* xpb = (unsigned short*)(ws + XP_BYTES);
    unsigned long long* hpk = (unsigned long long*)(ws + H_OFF);
    float* outp = (float*)d_out;

    // zero tagged h state (both buffers => tag 0 == step-0 expected, data 0), every call
    hipMemsetAsync(ws + H_OFF, 0, HPK_BYTES, stream);

    gemm_xproj<<<dim3(24, 256, 2), dim3(256), 0, stream>>>(
        tokens, emb, W_fw, W_bw, bin_fw, bin_bw, xpf, xpb);

    void* args[] = { (void*)&xpf, (void*)&xpb, (void*)&U_fw, (void*)&U_bw,
                     (void*)&brc_fw, (void*)&brc_bw, (void*)&tokens,
                     (void*)&hpk, (void*)&outp };
    hipLaunchCooperativeKernel((const void*)gru_scan, dim3(64), dim3(512), args, 0, stream);
}

// Round 5
// 1911.936 us; speedup vs baseline: 2.8462x; 1.2039x over previous
//
#include <hip/hip_runtime.h>
#include <stdint.h>

#define B_ 32
#define T_ 512
#define E_ 256
#define U_ 512
#define N3U_ 1536

typedef __bf16 bf16_t;
typedef bf16_t bf16x8 __attribute__((ext_vector_type(8)));
typedef float f32x4 __attribute__((ext_vector_type(4)));
typedef unsigned int u32x4 __attribute__((ext_vector_type(4)));

__device__ __forceinline__ unsigned short f2bf(float x) {
    union { float f; unsigned int u; } v; v.f = x;
    return (unsigned short)((v.u + 0x7fffu + ((v.u >> 16) & 1u)) >> 16);
}
__device__ __forceinline__ float bf2f(unsigned short h) {
    union { unsigned int u; float f; } v; v.u = ((unsigned int)h) << 16;
    return v.f;
}
// fast sigmoid/tanh on the serial critical path (v_exp_f32-based, branchless,
// overflow-safe; |err| ~1e-6 << 2^-10 tolerance). Proven in R4 (same absmax).
__device__ __forceinline__ float fsigmoid(float x) {
    return 1.f / (1.f + __expf(-x));
}
__device__ __forceinline__ float ftanh(float x) {
    float ax = fabsf(x);
    float e  = __expf(-2.f * ax);          // <= 1, no overflow
    float t  = (1.f - e) / (1.f + e);
    return copysignf(t, x);
}

// ---------- Kernel 1: xp[dir] = bf16( bf16(emb[tokens]) @ bf16(W) + b_in ) ----------
// (unchanged — proven)
__global__ __launch_bounds__(256) void gemm_xproj(
    const int* __restrict__ tokens, const float* __restrict__ emb,
    const float* __restrict__ Wf, const float* __restrict__ Wb,
    const float* __restrict__ binf, const float* __restrict__ binb,
    unsigned short* __restrict__ xpf, unsigned short* __restrict__ xpb)
{
    const int dir = blockIdx.z;
    const float* W   = dir ? Wb   : Wf;
    const float* bin = dir ? binb : binf;
    unsigned short* xp = dir ? xpb : xpf;

    const int n0 = blockIdx.x << 6;
    const int m0 = blockIdx.y << 6;
    const int tid  = threadIdx.x;
    const int lane = tid & 63;
    const int w    = tid >> 6;

    __shared__ __align__(16) unsigned short Ash[64][136];
    __shared__ __align__(16) unsigned short Bsh[64][136];

    f32x4 acc[4];
    for (int f = 0; f < 4; ++f) acc[f] = (f32x4){0.f, 0.f, 0.f, 0.f};

    for (int kt = 0; kt < 2; ++kt) {
        const int kbase = kt << 7;
        for (int p = 0; p < 8; ++p) {
            int row = (p << 3) + (tid >> 5);
            int c   = tid & 31;
            int tok = tokens[m0 + row];
            float4 v = *(const float4*)&emb[tok * E_ + kbase + (c << 2)];
            ushort4 o;
            o.x = f2bf(v.x); o.y = f2bf(v.y); o.z = f2bf(v.z); o.w = f2bf(v.w);
            *(ushort4*)&Ash[row][c << 2] = o;
        }
        for (int p = 0; p < 8; ++p) {
            int kl = (p << 4) + (tid >> 4);
            int j4 = (tid & 15) << 2;
            float4 v = *(const float4*)&W[(kbase + kl) * N3U_ + n0 + j4];
            Bsh[j4 + 0][kl] = f2bf(v.x);
            Bsh[j4 + 1][kl] = f2bf(v.y);
            Bsh[j4 + 2][kl] = f2bf(v.z);
            Bsh[j4 + 3][kl] = f2bf(v.w);
        }
        __syncthreads();
        for (int ks = 0; ks < 4; ++ks) {
            int off = (ks << 5) + ((lane >> 4) << 3);
            bf16x8 a = *(const bf16x8*)&Ash[(w << 4) + (lane & 15)][off];
            for (int f = 0; f < 4; ++f) {
                bf16x8 b = *(const bf16x8*)&Bsh[(f << 4) + (lane & 15)][off];
                acc[f] = __builtin_amdgcn_mfma_f32_16x16x32_bf16(a, b, acc[f], 0, 0, 0);
            }
        }
        __syncthreads();
    }
    const int col_l = lane & 15;
    const int mrow  = (w << 4) + ((lane >> 4) << 2);
    for (int f = 0; f < 4; ++f) {
        int col = n0 + (f << 4) + col_l;
        float bb = bin[col];
        for (int r = 0; r < 4; ++r) {
            int m = m0 + mrow + r;
            xp[m * N3U_ + col] = f2bf(acc[f][r] + bb);
        }
    }
}

// ---------- Kernel 2: bidirectional masked GRU scan, weight-stationary MFMA ----------
// R10 exchange protocol (sentinel + untagged payload). 64 blocks = dir(2) x mg(2) x
// us(16), 512 threads (8 waves: wk(4) k-quarter x wc(2) 16-col half) — R4's proven
// compute structure, only the communication changed:
//  * payload: dat[buf][dir][mg][16 rows][512 u] u32 {lo16|hi16}, written with
//    sc0sc1 atomic u32 stores (write-through to MALL), read with inline-asm
//    global_load_dwordx4 sc0 sc1 (4 requests/thread, half the bytes of R4's
//    tagged u64s).
//  * detection: per-producer sentinel u32 (value s+1, 64B-padded). Producer:
//    data stores -> s_waitcnt vmcnt(0) -> syncthreads -> tid0 sentinel store
//    (store order at the coherence point => sentinel implies data visible).
//    Consumer: each thread polls ONE sentinel (tid&15) -> syncthreads converges
//    the block (all 16 producers seen) -> bulk load.
// Lap-safety (same induction as R2/R4): a producer overwrites buffer X of step s
// only at end of step s+2; its start-of-(s+2) poll proves every block PUBLISHED
// step s+1, and publishing s+1 requires having READ buffer X (step s+1 reads X).
#define RED(wc, g, wk, row, col) (((((wc)*3 + (g))*4 + (wk))*16 + (row))*18 + (col))
__global__ __launch_bounds__(512, 2) void gru_scan(
    const unsigned short* __restrict__ xpf, const unsigned short* __restrict__ xpb,
    const float* __restrict__ Uf, const float* __restrict__ Ub,
    const float* __restrict__ brf, const float* __restrict__ brb,
    const int* __restrict__ tokens,
    unsigned int* __restrict__ dat,
    unsigned int* __restrict__ sent,
    float* __restrict__ out)
{
    const int bx  = blockIdx.x;
    const int us  = bx & 15;           // 16 u-slices of 32
    const int mg  = (bx >> 4) & 1;
    const int dir = bx >> 5;
    const int u0  = us << 5;
    const int tid  = threadIdx.x;
    const int lane = tid & 63;
    const int w    = tid >> 6;         // 0..7
    const int wk   = w & 3;            // k-quarter
    const int wc   = w >> 2;           // 16-col half
    const int group = (dir << 1) | mg;

    const unsigned short* xp = dir ? xpb : xpf;
    const float* Uw = dir ? Ub : Uf;
    const float* br = dir ? brb : brf;

    __shared__ __align__(16) unsigned short Ahi[16][520];
    __shared__ __align__(16) unsigned short Alo[16][520];
    __shared__ __align__(16) float red[2 * 3 * 4 * 16 * 18];   // 27.6 KB

    // stationary weights: wave (wk,wc): k in [wk*128,(wk+1)*128), cols = 3 gates x
    // 16 cols at u0 + wc*16
    bf16x8 wfrag[4][3];
    const int quad = lane >> 4, nl = lane & 15;
    for (int ks = 0; ks < 4; ++ks)
        for (int g = 0; g < 3; ++g) {
            union { bf16x8 v; unsigned short s[8]; } uu;
            for (int j = 0; j < 8; ++j) {
                int k   = (wk << 7) + (ks << 5) + (quad << 3) + j;
                int col = (g << 9) + u0 + (wc << 4) + nl;
                uu.s[j] = f2bf(Uw[k * N3U_ + col]);
            }
            wfrag[ks][g] = uu.v;
        }

    // epilogue ownership: 1 output per thread
    const int bl = tid >> 5;           // local batch row 0..15
    const int cl = tid & 31;           // local u 0..31
    const int ewc = cl >> 4, ec16 = cl & 15;
    const int bg = (mg << 4) + bl;     // global batch row
    const int ug = u0 + cl;            // global u
    float hreg = 0.f;
    const float brz = br[ug], brr = br[512 + ug], brh = br[1024 + ug];

    // bulk-load addressing: 4 passes of dwordx4; pass p: row=(tid>>7)+4p, col4=(tid&127)*4
    const int lrow0 = tid >> 7;
    const int lcol4 = (tid & 127) << 2;
    // sentinel this thread polls (one of 16 producers), 16-dword (64B) padding
    const int spoll = (group << 8) + ((tid & 15) << 4);
    const int sown  = (group << 8) + (us << 4);

    for (int s = 0; s < T_; ++s) {
        const int t    = dir ? (T_ - 1 - s) : s;
        const int bufr = s & 1, bufw = bufr ^ 1;

        // early independent loads (consumed in epilogue)
        const int xrow = (bg * T_ + t) * N3U_;
        const unsigned short xzu = xp[xrow + ug];
        const unsigned short xru = xp[xrow + 512 + ug];
        const unsigned short xhu = xp[xrow + 1024 + ug];
        const int tok = tokens[bg * T_ + t];

        // ---- detect: poll my one sentinel until >= s ----
        {
            unsigned int sv = __hip_atomic_load(&sent[spoll],
                                __ATOMIC_RELAXED, __HIP_MEMORY_SCOPE_AGENT);
            while (sv < (unsigned int)s) {
                __builtin_amdgcn_s_sleep(1);
                sv = __hip_atomic_load(&sent[spoll],
                        __ATOMIC_RELAXED, __HIP_MEMORY_SCOPE_AGENT);
            }
        }
        __syncthreads();   // all 16 producers' sentinels observed across the block

        // ---- bulk-load payload: 4 x dwordx4 sc0 sc1 (MALL-coherent) ----
        const int dbase_r = (((bufr << 1) + dir) << 1 | mg) << 13;   // *8192 u32
        u32x4 pv0, pv1, pv2, pv3;
        {
            const unsigned int* a0 = dat + dbase_r + ((lrow0 +  0) << 9) + lcol4;
            const unsigned int* a1 = dat + dbase_r + ((lrow0 +  4) << 9) + lcol4;
            const unsigned int* a2 = dat + dbase_r + ((lrow0 +  8) << 9) + lcol4;
            const unsigned int* a3 = dat + dbase_r + ((lrow0 + 12) << 9) + lcol4;
            asm volatile("global_load_dwordx4 %0, %1, off sc0 sc1" : "=v"(pv0) : "v"(a0) : "memory");
            asm volatile("global_load_dwordx4 %0, %1, off sc0 sc1" : "=v"(pv1) : "v"(a1) : "memory");
            asm volatile("global_load_dwordx4 %0, %1, off sc0 sc1" : "=v"(pv2) : "v"(a2) : "memory");
            asm volatile("global_load_dwordx4 %0, %1, off sc0 sc1" : "=v"(pv3) : "v"(a3) : "memory");
            asm volatile("s_waitcnt vmcnt(0)" ::: "memory");
            __builtin_amdgcn_sched_barrier(0);   // rule #18: keep unpack below the wait
        }
        // unpack to LDS planes (8B stores)
        {
            ushort4 h4, l4;
#define UNP(PV, ROWOFF)                                                        \
            h4.x = (unsigned short)(PV.x & 0xffffu); l4.x = (unsigned short)(PV.x >> 16); \
            h4.y = (unsigned short)(PV.y & 0xffffu); l4.y = (unsigned short)(PV.y >> 16); \
            h4.z = (unsigned short)(PV.z & 0xffffu); l4.z = (unsigned short)(PV.z >> 16); \
            h4.w = (unsigned short)(PV.w & 0xffffu); l4.w = (unsigned short)(PV.w >> 16); \
            *(ushort4*)&Ahi[lrow0 + ROWOFF][lcol4] = h4;                        \
            *(ushort4*)&Alo[lrow0 + ROWOFF][lcol4] = l4;
            UNP(pv0, 0) UNP(pv1, 4) UNP(pv2, 8) UNP(pv3, 12)
#undef UNP
        }
        __syncthreads();

        f32x4 acc[3];
        acc[0] = (f32x4){0.f,0.f,0.f,0.f};
        acc[1] = (f32x4){0.f,0.f,0.f,0.f};
        acc[2] = (f32x4){0.f,0.f,0.f,0.f};
        for (int ks = 0; ks < 4; ++ks) {
            int off = (wk << 7) + (ks << 5) + (quad << 3);
            bf16x8 ahi = *(const bf16x8*)&Ahi[nl][off];
            bf16x8 alo = *(const bf16x8*)&Alo[nl][off];
#pragma unroll
            for (int g = 0; g < 3; ++g) {
                acc[g] = __builtin_amdgcn_mfma_f32_16x16x32_bf16(ahi, wfrag[ks][g], acc[g], 0, 0, 0);
                acc[g] = __builtin_amdgcn_mfma_f32_16x16x32_bf16(alo, wfrag[ks][g], acc[g], 0, 0, 0);
            }
        }
        // k-split partials to LDS: row=(quad*4+r), col=nl for this (wc,wk)
#pragma unroll
        for (int g = 0; g < 3; ++g)
#pragma unroll
            for (int r = 0; r < 4; ++r)
                red[RED(wc, g, wk, (quad << 2) + r, nl)] = acc[g][r];
        __syncthreads();

        // per-thread epilogue (1 output)
        float rz = brz, rr = brr, rh = brh;
#pragma unroll
        for (int k4 = 0; k4 < 4; ++k4) {
            rz += red[RED(ewc, 0, k4, bl, ec16)];
            rr += red[RED(ewc, 1, k4, bl, ec16)];
            rh += red[RED(ewc, 2, k4, bl, ec16)];
        }
        float xz = bf2f(xzu), xr = bf2f(xru), xh = bf2f(xhu);
        float z    = fsigmoid(xz + rz);
        float rg   = fsigmoid(xr + rr);
        float cand = ftanh(xh + rg * rh);
        float hn   = z * hreg + (1.f - z) * cand;
        float ho   = (tok != 0) ? hn : hreg;   // Keras masking: carry state
        hreg = ho;

        // ---- publish: data store -> drain -> block barrier -> sentinel ----
        unsigned short hi = f2bf(ho);
        unsigned short lo = f2bf(ho - bf2f(hi));
        const int dbase_w = (((bufw << 1) + dir) << 1 | mg) << 13;
        __hip_atomic_store(&dat[dbase_w + (bl << 9) + ug],
                           ((unsigned int)lo << 16) | (unsigned int)hi,
                           __ATOMIC_RELAXED, __HIP_MEMORY_SCOPE_AGENT);
        asm volatile("s_waitcnt vmcnt(0)" ::: "memory");
        __syncthreads();
        if (tid == 0)
            __hip_atomic_store(&sent[sown], (unsigned int)(s + 1),
                               __ATOMIC_RELAXED, __HIP_MEMORY_SCOPE_AGENT);

        out[(bg * T_ + t) * 1024 + (dir << 9) + ug] = ho;   // off critical path
    }
}

extern "C" void kernel_launch(void* const* d_in, const int* in_sizes, int n_in,
                              void* d_out, int out_size, void* d_ws, size_t ws_size,
                              hipStream_t stream)
{
    const size_t XP_BYTES  = (size_t)B_ * T_ * N3U_ * 2;    // 50,331,648 per dir (bf16)
    const size_t DAT_OFF   = 2 * XP_BYTES;                  // 100,663,296
    const size_t DAT_BYTES = (size_t)2 * 2 * 2 * 16 * 512 * 4; // 262,144 (2 bufs x 2 dirs x 2 mg)
    const size_t SENT_OFF  = DAT_OFF + DAT_BYTES;
    const size_t SENT_BYTES = 4 * 16 * 64;                  // 4 groups x 16 producers x 64B
    const size_t NEED      = SENT_OFF + SENT_BYTES;
    if (ws_size < NEED) return;  // fail visibly

    const int*   tokens = (const int*)d_in[0];
    const float* emb    = (const float*)d_in[1];
    const float* W_fw   = (const float*)d_in[2];
    const float* U_fw   = (const float*)d_in[3];
    const float* bin_fw = (const float*)d_in[4];
    const float* brc_fw = (const float*)d_in[5];
    const float* W_bw   = (const float*)d_in[6];
    const float* U_bw   = (const float*)d_in[7];
    const float* bin_bw = (const float*)d_in[8];
    const float* brc_bw = (const float*)d_in[9];

    char* ws = (char*)d_ws;
    unsigned short* xpf = (unsigned short*)ws;
    unsigned short* xpb = (unsigned short*)(ws + XP_BYTES);
    unsigned int*   dat  = (unsigned int*)(ws + DAT_OFF);
    unsigned int*   sent = (unsigned int*)(ws + SENT_OFF);
    float* outp = (float*)d_out;

    // zero payload (both buffers => step-0 h = 0) + sentinels (=> poll >=0 passes)
    hipMemsetAsync(ws + DAT_OFF, 0, DAT_BYTES + SENT_BYTES, stream);

    gemm_xproj<<<dim3(24, 256, 2), dim3(256), 0, stream>>>(
        tokens, emb, W_fw, W_bw, bin_fw, bin_bw, xpf, xpb);

    void* args[] = { (void*)&xpf, (void*)&xpb, (void*)&U_fw, (void*)&U_bw,
                     (void*)&brc_fw, (void*)&brc_bw, (void*)&tokens,
                     (void*)&dat, (void*)&sent, (void*)&outp };
    hipLaunchCooperativeKernel((const void*)gru_scan, dim3(64), dim3(512), args, 0, stream);
}

// Round 9
// 1784.782 us; speedup vs baseline: 3.0490x; 1.0712x over previous
//
#include <hip/hip_runtime.h>
#include <stdint.h>

#define B_ 32
#define T_ 512
#define E_ 256
#define U_ 512
#define N3U_ 1536

typedef __bf16 bf16_t;
typedef bf16_t bf16x8 __attribute__((ext_vector_type(8)));
typedef float f32x4 __attribute__((ext_vector_type(4)));
typedef unsigned int u32x4 __attribute__((ext_vector_type(4)));

__device__ __forceinline__ unsigned short f2bf(float x) {
    union { float f; unsigned int u; } v; v.f = x;
    return (unsigned short)((v.u + 0x7fffu + ((v.u >> 16) & 1u)) >> 16);
}
__device__ __forceinline__ float bf2f(unsigned short h) {
    union { unsigned int u; float f; } v; v.u = ((unsigned int)h) << 16;
    return v.f;
}
// fast sigmoid/tanh (proven R4/R5, same absmax)
__device__ __forceinline__ float fsigmoid(float x) {
    return 1.f / (1.f + __expf(-x));
}
__device__ __forceinline__ float ftanh(float x) {
    float ax = fabsf(x);
    float e  = __expf(-2.f * ax);
    float t  = (1.f - e) / (1.f + e);
    return copysignf(t, x);
}

// ---------- Kernel 1: xp[dir] = bf16( bf16(emb[tokens]) @ bf16(W) + b_in ) ----------
// (unchanged — proven)
__global__ __launch_bounds__(256) void gemm_xproj(
    const int* __restrict__ tokens, const float* __restrict__ emb,
    const float* __restrict__ Wf, const float* __restrict__ Wb,
    const float* __restrict__ binf, const float* __restrict__ binb,
    unsigned short* __restrict__ xpf, unsigned short* __restrict__ xpb)
{
    const int dir = blockIdx.z;
    const float* W   = dir ? Wb   : Wf;
    const float* bin = dir ? binb : binf;
    unsigned short* xp = dir ? xpb : xpf;

    const int n0 = blockIdx.x << 6;
    const int m0 = blockIdx.y << 6;
    const int tid  = threadIdx.x;
    const int lane = tid & 63;
    const int w    = tid >> 6;

    __shared__ __align__(16) unsigned short Ash[64][136];
    __shared__ __align__(16) unsigned short Bsh[64][136];

    f32x4 acc[4];
    for (int f = 0; f < 4; ++f) acc[f] = (f32x4){0.f, 0.f, 0.f, 0.f};

    for (int kt = 0; kt < 2; ++kt) {
        const int kbase = kt << 7;
        for (int p = 0; p < 8; ++p) {
            int row = (p << 3) + (tid >> 5);
            int c   = tid & 31;
            int tok = tokens[m0 + row];
            float4 v = *(const float4*)&emb[tok * E_ + kbase + (c << 2)];
            ushort4 o;
            o.x = f2bf(v.x); o.y = f2bf(v.y); o.z = f2bf(v.z); o.w = f2bf(v.w);
            *(ushort4*)&Ash[row][c << 2] = o;
        }
        for (int p = 0; p < 8; ++p) {
            int kl = (p << 4) + (tid >> 4);
            int j4 = (tid & 15) << 2;
            float4 v = *(const float4*)&W[(kbase + kl) * N3U_ + n0 + j4];
            Bsh[j4 + 0][kl] = f2bf(v.x);
            Bsh[j4 + 1][kl] = f2bf(v.y);
            Bsh[j4 + 2][kl] = f2bf(v.z);
            Bsh[j4 + 3][kl] = f2bf(v.w);
        }
        __syncthreads();
        for (int ks = 0; ks < 4; ++ks) {
            int off = (ks << 5) + ((lane >> 4) << 3);
            bf16x8 a = *(const bf16x8*)&Ash[(w << 4) + (lane & 15)][off];
            for (int f = 0; f < 4; ++f) {
                bf16x8 b = *(const bf16x8*)&Bsh[(f << 4) + (lane & 15)][off];
                acc[f] = __builtin_amdgcn_mfma_f32_16x16x32_bf16(a, b, acc[f], 0, 0, 0);
            }
        }
        __syncthreads();
    }
    const int col_l = lane & 15;
    const int mrow  = (w << 4) + ((lane >> 4) << 2);
    for (int f = 0; f < 4; ++f) {
        int col = n0 + (f << 4) + col_l;
        float bb = bin[col];
        for (int r = 0; r < 4; ++r) {
            int m = m0 + mrow + r;
            xp[m * N3U_ + col] = f2bf(acc[f][r] + bb);
        }
    }
}

// ---------- Kernel 2: bidirectional masked GRU scan, weight-stationary MFMA ----------
// R14: sentinel-free tagged exchange (R13 protocol) with the R5-proven FULL 16-row
// staging (R13's bug: it staged only rows 0-7, leaving half the A matrix
// uninitialized — caught by diffing against the last passing kernel).
// Geometry identical to PASSED R5: 64 blocks = dir(2) x mg(2) x us(16), 512 threads
// (8 waves: wk(4) k-quarter x wc(2) 16-col half).
// Exchange: each h value is one u32 {lo16&0xFFFE | tagbit, hi16}, stored sc0 sc1
// (write-through to MALL, fire-and-forget: no drain, no barrier, no sentinel).
// Tag consumed at step s = (s>>1)&1. Skew induction (every consumer reads every
// producer's slice each step) bounds skew to <=1, so buffer s&1 holds either the
// end-of-(s-1) write (tag (s>>1)&1) or the end-of-(s-3) write (tag ((s-2)>>1)&1)
// — always different in bit 0. Init: buf0 = 0x00 (tag 0 + h=0, valid step-0
// state); buf1 = 0x01 bytes (tag 1 != step-1 expectation 0 => retry until real
// data lands). Tag+data share a u32 => single-copy atomic, no torn reads.
// Retry is purely data-dependent => structurally hang-free.
// Two __syncthreads/step: (1) post-unpack (Ahi/Alo writes before MFMA reads; also
// orders prev-step red reads before this step's red writes), (2) post-red
// (partials before epilogue reads; also orders MFMA LDS reads before next-step
// Ahi/Alo overwrite).
#define RED(wc, g, wk, row, col) (((((wc)*3 + (g))*4 + (wk))*16 + (row))*18 + (col))
#define TAGBAD4(PV, E16) ((((PV[0] ^ (E16)) | (PV[1] ^ (E16)) | (PV[2] ^ (E16)) | (PV[3] ^ (E16))) >> 16) & 1u)
__global__ __launch_bounds__(512, 2) void gru_scan(
    const unsigned short* __restrict__ xpf, const unsigned short* __restrict__ xpb,
    const float* __restrict__ Uf, const float* __restrict__ Ub,
    const float* __restrict__ brf, const float* __restrict__ brb,
    const int* __restrict__ tokens,
    unsigned int* __restrict__ dat,
    float* __restrict__ out)
{
    const int bx  = blockIdx.x;
    const int us  = bx & 15;           // 16 u-slices of 32
    const int mg  = (bx >> 4) & 1;
    const int dir = bx >> 5;
    const int u0  = us << 5;
    const int tid  = threadIdx.x;
    const int lane = tid & 63;
    const int w    = tid >> 6;         // 0..7
    const int wk   = w & 3;            // k-quarter
    const int wc   = w >> 2;           // 16-col half

    const unsigned short* xp = dir ? xpb : xpf;
    const float* Uw = dir ? Ub : Uf;
    const float* br = dir ? brb : brf;

    __shared__ __align__(16) unsigned short Ahi[16][520];
    __shared__ __align__(16) unsigned short Alo[16][520];
    __shared__ __align__(16) float red[2 * 3 * 4 * 16 * 18];   // 27.6 KB

    // stationary weights: wave (wk,wc): k in [wk*128,(wk+1)*128), cols = 3 gates x
    // 16 cols at u0 + wc*16
    bf16x8 wfrag[4][3];
    const int quad = lane >> 4, nl = lane & 15;
    for (int ks = 0; ks < 4; ++ks)
        for (int g = 0; g < 3; ++g) {
            union { bf16x8 v; unsigned short s[8]; } uu;
            for (int j = 0; j < 8; ++j) {
                int k   = (wk << 7) + (ks << 5) + (quad << 3) + j;
                int col = (g << 9) + u0 + (wc << 4) + nl;
                uu.s[j] = f2bf(Uw[k * N3U_ + col]);
            }
            wfrag[ks][g] = uu.v;
        }

    // epilogue ownership: 1 output per thread
    const int bl = tid >> 5;           // local batch row 0..15
    const int cl = tid & 31;           // local u 0..31
    const int ewc = cl >> 4, ec16 = cl & 15;
    const int bg = (mg << 4) + bl;     // global batch row
    const int ug = u0 + cl;            // global u
    float hreg = 0.f;
    const float brz = br[ug], brr = br[512 + ug], brh = br[1024 + ug];

    // bulk-load addressing: 4 x dwordx4/thread, rows lrow0+{0,4,8,12} (ALL 16 rows)
    const int lrow0 = tid >> 7;              // 0..3
    const int lcol4 = (tid & 127) << 2;      // u32 col 0..508

    for (int s = 0; s < T_; ++s) {
        const int t    = dir ? (T_ - 1 - s) : s;
        const int bufr = s & 1;

        // early independent loads (consumed in epilogue)
        const int xrow = (bg * T_ + t) * N3U_;
        const unsigned short xzu = xp[xrow + ug];
        const unsigned short xru = xp[xrow + 512 + ug];
        const unsigned short xhu = xp[xrow + 1024 + ug];
        const int tok = tokens[bg * T_ + t];

        // ---- speculative tagged bulk load + retry (no sentinel, no pre-barrier) ----
        const int dbase_r = (((bufr << 1) + dir) << 1 | mg) << 13;   // *8192 u32
        const unsigned int exp16 = (((unsigned int)s >> 1) & 1u) << 16;
        const unsigned int* a0 = dat + dbase_r + ((lrow0 +  0) << 9) + lcol4;
        const unsigned int* a1 = dat + dbase_r + ((lrow0 +  4) << 9) + lcol4;
        const unsigned int* a2 = dat + dbase_r + ((lrow0 +  8) << 9) + lcol4;
        const unsigned int* a3 = dat + dbase_r + ((lrow0 + 12) << 9) + lcol4;
        u32x4 pv0, pv1, pv2, pv3;
        asm volatile("global_load_dwordx4 %0, %1, off sc0 sc1" : "=v"(pv0) : "v"(a0) : "memory");
        asm volatile("global_load_dwordx4 %0, %1, off sc0 sc1" : "=v"(pv1) : "v"(a1) : "memory");
        asm volatile("global_load_dwordx4 %0, %1, off sc0 sc1" : "=v"(pv2) : "v"(a2) : "memory");
        asm volatile("global_load_dwordx4 %0, %1, off sc0 sc1" : "=v"(pv3) : "v"(a3) : "memory");
        asm volatile("s_waitcnt vmcnt(0)" ::: "memory");
        unsigned int bad0 = TAGBAD4(pv0, exp16);
        unsigned int bad1 = TAGBAD4(pv1, exp16);
        unsigned int bad2 = TAGBAD4(pv2, exp16);
        unsigned int bad3 = TAGBAD4(pv3, exp16);
        while (bad0 | bad1 | bad2 | bad3) {
            __builtin_amdgcn_s_sleep(1);
            if (bad0) asm volatile("global_load_dwordx4 %0, %1, off sc0 sc1" : "=v"(pv0) : "v"(a0) : "memory");
            if (bad1) asm volatile("global_load_dwordx4 %0, %1, off sc0 sc1" : "=v"(pv1) : "v"(a1) : "memory");
            if (bad2) asm volatile("global_load_dwordx4 %0, %1, off sc0 sc1" : "=v"(pv2) : "v"(a2) : "memory");
            if (bad3) asm volatile("global_load_dwordx4 %0, %1, off sc0 sc1" : "=v"(pv3) : "v"(a3) : "memory");
            asm volatile("s_waitcnt vmcnt(0)" ::: "memory");
            bad0 = TAGBAD4(pv0, exp16);
            bad1 = TAGBAD4(pv1, exp16);
            bad2 = TAGBAD4(pv2, exp16);
            bad3 = TAGBAD4(pv3, exp16);
        }
        __builtin_amdgcn_sched_barrier(0);   // rule #18: keep unpack below the wait

        // unpack to LDS planes (tag bit left in lo LSB: <=2^-17 relative, negligible)
        {
            ushort4 h4, l4;
#define UNP(PV, ROWOFF)                                                        \
            h4.x = (unsigned short)(PV[0] & 0xffffu); l4.x = (unsigned short)(PV[0] >> 16); \
            h4.y = (unsigned short)(PV[1] & 0xffffu); l4.y = (unsigned short)(PV[1] >> 16); \
            h4.z = (unsigned short)(PV[2] & 0xffffu); l4.z = (unsigned short)(PV[2] >> 16); \
            h4.w = (unsigned short)(PV[3] & 0xffffu); l4.w = (unsigned short)(PV[3] >> 16); \
            *(ushort4*)&Ahi[lrow0 + ROWOFF][lcol4] = h4;                        \
            *(ushort4*)&Alo[lrow0 + ROWOFF][lcol4] = l4;
            UNP(pv0, 0) UNP(pv1, 4) UNP(pv2, 8) UNP(pv3, 12)
#undef UNP
        }
        __syncthreads();   // barrier 1: unpack complete before MFMA reads

        f32x4 acc[3];
        acc[0] = (f32x4){0.f,0.f,0.f,0.f};
        acc[1] = (f32x4){0.f,0.f,0.f,0.f};
        acc[2] = (f32x4){0.f,0.f,0.f,0.f};
        for (int ks = 0; ks < 4; ++ks) {
            int off = (wk << 7) + (ks << 5) + (quad << 3);
            bf16x8 ahi = *(const bf16x8*)&Ahi[nl][off];
            bf16x8 alo = *(const bf16x8*)&Alo[nl][off];
#pragma unroll
            for (int g = 0; g < 3; ++g) {
                acc[g] = __builtin_amdgcn_mfma_f32_16x16x32_bf16(ahi, wfrag[ks][g], acc[g], 0, 0, 0);
                acc[g] = __builtin_amdgcn_mfma_f32_16x16x32_bf16(alo, wfrag[ks][g], acc[g], 0, 0, 0);
            }
        }
        // k-split partials to LDS: row=(quad*4+r), col=nl for this (wc,wk)
#pragma unroll
        for (int g = 0; g < 3; ++g)
#pragma unroll
            for (int r = 0; r < 4; ++r)
                red[RED(wc, g, wk, (quad << 2) + r, nl)] = acc[g][r];
        __syncthreads();   // barrier 2: partials complete before epilogue reads

        // per-thread epilogue (1 output)
        float rz = brz, rr = brr, rh = brh;
#pragma unroll
        for (int k4 = 0; k4 < 4; ++k4) {
            rz += red[RED(ewc, 0, k4, bl, ec16)];
            rr += red[RED(ewc, 1, k4, bl, ec16)];
            rh += red[RED(ewc, 2, k4, bl, ec16)];
        }
        float xz = bf2f(xzu), xr = bf2f(xru), xh = bf2f(xhu);
        float z    = fsigmoid(xz + rz);
        float rg   = fsigmoid(xr + rr);
        float cand = ftanh(xh + rg * rh);
        float hn   = z * hreg + (1.f - z) * cand;
        float ho   = (tok != 0) ? hn : hreg;   // Keras masking: carry state
        hreg = ho;

        // ---- publish: ONE tagged fire-and-forget store (no drain/barrier/sentinel) ----
        unsigned short hi = f2bf(ho);
        unsigned short lo = f2bf(ho - bf2f(hi));
        unsigned int wtag = ((unsigned int)(s + 1) >> 1) & 1u;
        unsigned int pv   = ((((unsigned int)lo & 0xFFFEu) | wtag) << 16) | (unsigned int)hi;
        const int dbase_w = ((((bufr ^ 1) << 1) + dir) << 1 | mg) << 13;
        unsigned int* dp  = dat + dbase_w + (bl << 9) + ug;
        asm volatile("global_store_dword %0, %1, off sc0 sc1" :: "v"(dp), "v"(pv) : "memory");

        out[(bg * T_ + t) * 1024 + (dir << 9) + ug] = ho;   // off critical path
    }
}

extern "C" void kernel_launch(void* const* d_in, const int* in_sizes, int n_in,
                              void* d_out, int out_size, void* d_ws, size_t ws_size,
                              hipStream_t stream)
{
    const size_t XP_BYTES  = (size_t)B_ * T_ * N3U_ * 2;    // 50,331,648 per dir (bf16)
    const size_t DAT_OFF   = 2 * XP_BYTES;                  // 100,663,296
    const size_t DAT_BYTES = (size_t)2 * 2 * 2 * 16 * 512 * 4; // 262,144 (2 bufs x 2 dirs x 2 mg)
    const size_t NEED      = DAT_OFF + DAT_BYTES;
    if (ws_size < NEED) return;  // fail visibly

    const int*   tokens = (const int*)d_in[0];
    const float* emb    = (const float*)d_in[1];
    const float* W_fw   = (const float*)d_in[2];
    const float* U_fw   = (const float*)d_in[3];
    const float* bin_fw = (const float*)d_in[4];
    const float* brc_fw = (const float*)d_in[5];
    const float* W_bw   = (const float*)d_in[6];
    const float* U_bw   = (const float*)d_in[7];
    const float* bin_bw = (const float*)d_in[8];
    const float* brc_bw = (const float*)d_in[9];

    char* ws = (char*)d_ws;
    unsigned short* xpf = (unsigned short*)ws;
    unsigned short* xpb = (unsigned short*)(ws + XP_BYTES);
    unsigned int*   dat = (unsigned int*)(ws + DAT_OFF);
    float* outp = (float*)d_out;

    // buffer0 (first half): 0x00 => tag 0, h=0 — valid step-0 state.
    // buffer1 (second half): 0x01 bytes => u32 0x01010101, tag bit (bit16) = 1 —
    // cannot false-match step 1's expected tag 0; real writes overwrite it.
    hipMemsetAsync(ws + DAT_OFF, 0x00, DAT_BYTES / 2, stream);
    hipMemsetAsync(ws + DAT_OFF + DAT_BYTES / 2, 0x01, DAT_BYTES / 2, stream);

    gemm_xproj<<<dim3(24, 256, 2), dim3(256), 0, stream>>>(
        tokens, emb, W_fw, W_bw, bin_fw, bin_bw, xpf, xpb);

    void* args[] = { (void*)&xpf, (void*)&xpb, (void*)&U_fw, (void*)&U_bw,
                     (void*)&brc_fw, (void*)&brc_bw, (void*)&tokens,
                     (void*)&dat, (void*)&outp };
    hipLaunchCooperativeKernel((const void*)gru_scan, dim3(64), dim3(512), args, 0, stream);
}